// Round 1
// baseline (431.461 us; speedup 1.0000x reference)
//
#include <hip/hip_runtime.h>

// QB sparse gating forward, round 6.
// ONE WAVE PER ROW (131072 waves), coalesced float4 per lane.
//
// Round-6 changes vs round 5 (theory: kernel should be HBM-bound at ~90us;
// any excess is VGPR pressure / cache pollution, not the search chain):
//  1. exp() hoisted BEFORE the threshold search. exp(raw) does not depend on
//     selection, so raw[]/bb[] die right after key+exp computation. Live set
//     through the search drops to {key[8], e[8], addr} ~= 30 VGPRs -> fits
//     the 64-VGPR budget of __launch_bounds__(256,8) without scratch spills,
//     and the post-search critical path loses 8 transcendentals.
//  2. sel[8] bool array -> single bitmask register (VGPR pressure).
//  3. Nontemporal stores for the output: write-once-never-read stream; keep
//     it from thrashing L2/LLC against the logits read stream. Logits loads
//     stay cached (cross-iteration LLC reuse is possible if the harness fill
//     doesn't evict everything; nt-load would forfeit that for no gain).
//
// Selection: 4-way threshold search on 32-bit sortable keys of (logit-beta):
// 3 thresholds/iter (24 independent v_cmp ballots; counts + interval logic on
// the co-issued SALU), first iteration uses distribution-informed thresholds
// (rank-8 of 512 N(0,sqrt2) ~ 3.1+-0.4) -> typ. ~3 iterations. Correct for
// any data; exact-tie fallback fills slots in slot/lane order.
// Softmax over selected RAW logits without max-subtract (|logits|<=~6).

constexpr int M_DIM = 512;

typedef float f32x4 __attribute__((ext_vector_type(4)));

template<int CTRL, int RMASK>
__device__ __forceinline__ float wsum_step(float v) {
    int y = __builtin_amdgcn_update_dpp(0, __float_as_int(v), CTRL, RMASK, 0xF, true);
    return v + __int_as_float(y);
}

// wave64 float sum; uniform result via readlane 63
__device__ __forceinline__ float wave_sum_f32(float v) {
    v = wsum_step<0x111, 0xF>(v);
    v = wsum_step<0x112, 0xF>(v);
    v = wsum_step<0x114, 0xF>(v);
    v = wsum_step<0x118, 0xF>(v);
    v = wsum_step<0x142, 0xA>(v);
    v = wsum_step<0x143, 0xC>(v);
    return __int_as_float(__builtin_amdgcn_readlane(__float_as_int(v), 63));
}

__global__ __launch_bounds__(256, 8)
void qb_gating_kernel(const float* __restrict__ logits,
                      const float* __restrict__ beta,
                      float* __restrict__ out,
                      int nrows)
{
    const int lane = threadIdx.x & 63;
    const int row  = (int)((blockIdx.x * blockDim.x + threadIdx.x) >> 6);
    if (row >= nrows) return;

    const int base0 = 4 * lane;        // cols for slots 0..3
    const int base1 = 256 + 4 * lane;  // cols for slots 4..7

    const float* rp = logits + (size_t)row * M_DIM;
    const float4 r0 = *(const float4*)(rp + base0);
    const float4 r1 = *(const float4*)(rp + base1);
    const float4 b0 = *(const float4*)(beta + base0);
    const float4 b1 = *(const float4*)(beta + base1);

    const float raw[8] = {r0.x, r0.y, r0.z, r0.w, r1.x, r1.y, r1.z, r1.w};
    const float bb[8]  = {b0.x, b0.y, b0.z, b0.w, b1.x, b1.y, b1.z, b1.w};

    // order-preserving u32 keys of the debiased scores + selection-independent
    // exp of the raw logits. raw/bb are dead after this loop -> low pressure
    // through the search.
    unsigned key[8];
    float e[8];
#pragma unroll
    for (int s = 0; s < 8; ++s) {
        const int u = __float_as_int(raw[s] - bb[s]);
        key[s] = (unsigned)(u ^ ((u >> 31) | 0x80000000));
        e[s] = __expf(raw[s]);
    }

    // 4-way search: find T with count(key >= T) == 8
    // invariant: count(>=lo) >= 8, count(>=hi) < 8
    unsigned lo = 0u, hi = 0xFFFFFFFFu, T = 0u;
    bool found = false;
    // first-iteration thresholds: keys of adjusted scores {2.3, 3.05, 3.8}
    unsigned m1 = 0xC0133333u, m2 = 0xC0433333u, m3 = 0xC0733333u;
    while (hi - lo > 1u) {
        int c1c = 0, c2c = 0, c3c = 0;
#pragma unroll
        for (int s = 0; s < 8; ++s) {
            c1c += __popcll(__ballot(key[s] >= m1));
            c2c += __popcll(__ballot(key[s] >= m2));
            c3c += __popcll(__ballot(key[s] >= m3));
        }
        if (c1c == 8) { T = m1; found = true; break; }
        if (c2c == 8) { T = m2; found = true; break; }
        if (c3c == 8) { T = m3; found = true; break; }
        if      (c3c > 8) { lo = m3; }
        else if (c2c > 8) { lo = m2; hi = m3; }
        else if (c1c > 8) { lo = m1; hi = m2; }
        else              { hi = m1; }
        const unsigned span = hi - lo;
        m1 = lo + (span >> 2);
        m2 = lo + (span >> 1);
        m3 = lo + (span >> 1) + (span >> 2);
        if (m1 == lo) m1 = lo + 1u;   // degenerate interval -> binary-ish
        if (m2 <= m1) m2 = m1;        // duplicate thresholds harmless
        if (m3 <= m2) m3 = m2;
    }

    unsigned selm = 0u;               // bit s = slot s selected
    if (found) {
#pragma unroll
        for (int s = 0; s < 8; ++s) selm |= (key[s] >= T) ? (1u << s) : 0u;
    } else {
        // bitwise ties at key==lo straddle rank 8/9: take strict-greater,
        // fill remaining from tied keys in slot-major / lane order.
        int need = 8;
#pragma unroll
        for (int s = 0; s < 8; ++s) {
            const bool g = key[s] > lo;
            selm |= g ? (1u << s) : 0u;
            need -= __popcll(__ballot(g));
        }
#pragma unroll
        for (int s = 0; s < 8; ++s) {
            const unsigned long long m = __ballot(key[s] == lo);
            int take = (int)__popcll(m);
            take = take < need ? take : need;
            const int pfx = (int)__builtin_amdgcn_mbcnt_hi(
                (unsigned)(m >> 32),
                __builtin_amdgcn_mbcnt_lo((unsigned)m, 0u));
            if ((key[s] == lo) && (pfx < take)) selm |= (1u << s);
            need -= take;
        }
    }

    // softmax over selected raw logits (exp already computed; mask + sum)
    float psum = 0.f;
#pragma unroll
    for (int s = 0; s < 8; ++s) {
        e[s] = (selm & (1u << s)) ? e[s] : 0.f;
        psum += e[s];
    }
    const float tot = wave_sum_f32(psum);
    const float inv = __builtin_amdgcn_rcpf(tot);

    float* op = out + (size_t)row * M_DIM;
    f32x4 o0 = { e[0]*inv, e[1]*inv, e[2]*inv, e[3]*inv };
    f32x4 o1 = { e[4]*inv, e[5]*inv, e[6]*inv, e[7]*inv };
    __builtin_nontemporal_store(o0, (f32x4*)(op + base0));
    __builtin_nontemporal_store(o1, (f32x4*)(op + base1));
}

extern "C" void kernel_launch(void* const* d_in, const int* in_sizes, int n_in,
                              void* d_out, int out_size, void* d_ws, size_t ws_size,
                              hipStream_t stream)
{
    const float* logits = (const float*)d_in[0];
    const float* beta   = (const float*)d_in[1];
    float*       out    = (float*)d_out;

    const int nrows = in_sizes[0] / M_DIM;        // 131072
    const int nblocks = (nrows + 3) / 4;          // 4 waves (rows) per block

    qb_gating_kernel<<<nblocks, 256, 0, stream>>>(logits, beta, out, nrows);
}